// Round 6
// baseline (3413.386 us; speedup 1.0000x reference)
//
#include <hip/hip_runtime.h>
#include <math.h>

#define NN 16384
#define SS 2048
#define TT 16
#define CHUNK 2048   // OpenBLAS sgemv_t_4.c: #define NBMAX 2048 (reduction blocking)

// np.tanh(f32) mimic: evaluate in f64, round once to f32 (~correctly rounded)
__device__ __forceinline__ float tanh_cr(float a) {
    return (float)tanh((double)a);
}

// OpenBLAS sgemv_t_microk_haswell-4.c tail, per column:
// one ymm acc (8 stripes, sequential vfmadd231ps chain), then
// vextractf128+vaddps  -> fold stride 4
// vhaddps              -> fold stride 1
// vhaddps              -> fold stride 2
__device__ __forceinline__ float fold8(float a) {
    a += __shfl_xor(a, 4, 64);
    a += __shfl_xor(a, 1, 64);
    a += __shfl_xor(a, 2, 64);
    return a;
}

// inp[s,t] -> inpT[t,s], f32: tanh(where(u >= 0.01f, u, 0))
__global__ void prep_inp(const float* __restrict__ in, float* __restrict__ inpT) {
    int i = blockIdx.x * blockDim.x + threadIdx.x;
    if (i < SS * TT) {
        int s = i / TT, t = i % TT;
        float v = in[i];
        v = (v >= 0.01f) ? v : 0.0f;
        inpT[t * SS + s] = tanh_cr(v);
    }
}

__global__ void map_init(int* __restrict__ map) {
    int i = blockIdx.x * blockDim.x + threadIdx.x;
    if (i < NN) map[i] = -1;
}

__global__ void map_scatter(const int* __restrict__ idx, int* __restrict__ map) {
    int s = blockIdx.x * blockDim.x + threadIdx.x;
    if (s < SS) map[idx[s]] = s;
}

// t=0: x0 = W[:, idx] @ inp0 ; K=2048 = one NBMAX chunk, 8 lanes/row,
// lane j owns stripe k === j (mod 8), sequential fmaf chain (256 terms).
__global__ __launch_bounds__(256) void step0(const float* __restrict__ W,
                                             const int* __restrict__ idx,
                                             const float* __restrict__ inp0,
                                             float* __restrict__ x_out,
                                             float* __restrict__ out) {
    int gid = blockIdx.x * blockDim.x + threadIdx.x;
    int row = gid >> 3;
    int j   = gid & 7;
    if (row >= NN) return;
    const float* __restrict__ wrow = W + (size_t)row * NN;
    float acc = 0.0f;
    #pragma unroll 16
    for (int k = j; k < SS; k += 8)
        acc = fmaf(wrow[idx[k]], inp0[k], acc);
    float y = fold8(acc);
    if (j == 0) {
        float v = (y >= 0.01f) ? y : 0.0f;
        v = tanh_cr(5.0f * v);
        x_out[row] = v;
        out[(size_t)row * TT + 0] = v;
    }
}

// t>=1: y = W @ x in 2048-element chunks (chunk dots added to y in order),
// 8 stripes per chunk, sequential fmaf within stripe (256 terms).
__global__ __launch_bounds__(256) void step_t(const float* __restrict__ W,
                                              const float* __restrict__ x_in,
                                              const float* __restrict__ inp_t,
                                              const int* __restrict__ map,
                                              float* __restrict__ x_out,
                                              float* __restrict__ out, int t) {
    int gid = blockIdx.x * blockDim.x + threadIdx.x;
    int row = gid >> 3;
    int j   = gid & 7;
    if (row >= NN) return;
    const float* __restrict__ wrow = W + (size_t)row * NN;
    float y = 0.0f;
    for (int c0 = 0; c0 < NN; c0 += CHUNK) {
        float acc = 0.0f;
        #pragma unroll 16
        for (int k = c0 + j; k < c0 + CHUNK; k += 8)
            acc = fmaf(wrow[k], x_in[k], acc);
        y += fold8(acc);   // per-chunk horizontal sum, chunks accumulated in order
    }
    if (j == 0) {
        int m = map[row];
        if (m >= 0) y += inp_t[m];
        float v = (y >= 0.01f) ? y : 0.0f;
        v = tanh_cr(5.0f * v);
        x_out[row] = v;
        out[(size_t)row * TT + t] = v;
    }
}

extern "C" void kernel_launch(void* const* d_in, const int* in_sizes, int n_in,
                              void* d_out, int out_size, void* d_ws, size_t ws_size,
                              hipStream_t stream) {
    const float* W    = (const float*)d_in[0];
    const float* intt = (const float*)d_in[1];
    const int*   idx  = (const int*)d_in[2];
    float* out = (float*)d_out;

    char* ws = (char*)d_ws;
    float* inpT = (float*)ws;                                   // T*S f32 (128 KiB)
    size_t off = (size_t)TT * SS * 4;
    int*   map  = (int*)(ws + off);                             // N ints (64 KiB)
    off += (size_t)NN * 4;
    float* xa   = (float*)(ws + off);                           // N f32
    float* xb   = xa + NN;                                      // N f32

    prep_inp<<<(SS * TT + 255) / 256, 256, 0, stream>>>(intt, inpT);
    map_init<<<NN / 256, 256, 0, stream>>>(map);
    map_scatter<<<SS / 256, 256, 0, stream>>>(idx, map);

    // 8 lanes per row -> N*8 threads -> 512 blocks of 256
    step0<<<NN * 8 / 256, 256, 0, stream>>>(W, idx, inpT, xa, out);

    float* xi_ = xa;
    float* xo_ = xb;
    for (int t = 1; t < TT; ++t) {
        step_t<<<NN * 8 / 256, 256, 0, stream>>>(W, xi_, inpT + (size_t)t * SS,
                                                 map, xo_, out, t);
        float* tmp = xi_; xi_ = xo_; xo_ = tmp;
    }
}